// Round 1
// baseline (180.558 us; speedup 1.0000x reference)
//
#include <hip/hip_runtime.h>
#include <hip/hip_bf16.h>
#include <math.h>

// Problem constants (from reference)
#define T_ 256
#define B_ 64
#define I_ 1024
#define L_ 2
#define G_ 4
#define H_ 1024
#define R_ 16
#define K2_ 2048   // I + H (concatenated GEMM K)
#define NTOT_ 4096 // G*H    (concatenated GEMM N)
#define KSPLIT_ 8
#define KCHUNK_ 256 // K2_/KSPLIT_

typedef __bf16 bf16x8 __attribute__((ext_vector_type(8)));
typedef float floatx4 __attribute__((ext_vector_type(4)));

// ---------------------------------------------------------------------------
// Kernel 1 (per layer): LoRA t-vectors + bf16 conversion of [x | h]
//   blocks 0..8191   : t[g,b,r] dot products (which = x-side / h-side)
//   blocks 8192..8703: convert xh fp32 -> bf16 into ws buffer [64][2048]
// ---------------------------------------------------------------------------
__global__ __launch_bounds__(64) void prep_kernel(
    const float* __restrict__ x_src,   // [B,1024] layer input x
    const float* __restrict__ h_src,   // [B,1024] h0[l]
    const float* __restrict__ A_x_l,   // [G,R,I]
    const float* __restrict__ A_h_l,   // [G,R,H]
    float* __restrict__ t_x,           // [G,B,R]
    float* __restrict__ t_h,           // [G,B,R]
    __bf16* __restrict__ xh)           // [B,2048] bf16
{
    int bid = blockIdx.x;
    if (bid < 8192) {
        int which = bid >> 12;          // 0: x-side, 1: h-side
        int rem = bid & 4095;
        int g = rem >> 10;
        int b = (rem >> 4) & 63;
        int r = rem & 15;
        const float* v = (which ? h_src : x_src) + b * 1024;
        const float* a = (which ? A_h_l : A_x_l) + (size_t)(g * R_ + r) * 1024;
        float s = 0.f;
        #pragma unroll 4
        for (int j = threadIdx.x; j < 1024; j += 64) s += v[j] * a[j];
        #pragma unroll
        for (int off = 32; off > 0; off >>= 1) s += __shfl_down(s, off);
        if (threadIdx.x == 0)
            (which ? t_h : t_x)[g * B_ * R_ + b * R_ + r] = s;
    } else {
        // conversion role: 512 blocks * 64 threads * 4 elems = 131072 = 64*2048
        int tid = (bid - 8192) * 64 + threadIdx.x;
        int e0 = tid * 4;
        int b = e0 >> 11;
        int k = e0 & 2047;
        const float* src = (k < 1024) ? (x_src + b * 1024 + k)
                                      : (h_src + b * 1024 + (k - 1024));
        float4 v = *(const float4*)src;
        __bf16* d = xh + b * 2048 + k;
        d[0] = (__bf16)v.x; d[1] = (__bf16)v.y;
        d[2] = (__bf16)v.z; d[3] = (__bf16)v.w;
    }
}

// ---------------------------------------------------------------------------
// Kernel 2 (per layer): split-K bf16 MFMA GEMM -> fp32 partials
//   grid (128 n-blocks, 8 k-splits), block = 128 threads (2 waves)
//   block tile: N=32 (16 per wave), M=64 (batch), K-chunk=256
//   partials: part[kb][m=64][n=4096]
// ---------------------------------------------------------------------------
__global__ __launch_bounds__(128) void gemm_kernel(
    const float* __restrict__ Wx_l,   // [G*H, 1024] fp32
    const float* __restrict__ Wh_l,   // [G*H, 1024] fp32
    const __bf16* __restrict__ xh,    // [64, 2048] bf16
    float* __restrict__ part)         // [8][64][4096] fp32
{
    __shared__ __bf16 Wl[32][264];    // +8 pad keeps 16B align, breaks stride
    __shared__ __bf16 Xl[64][264];

    const int nb = blockIdx.x;        // 0..127
    const int kb = blockIdx.y;        // 0..7
    const int n0 = nb * 32;
    const int tid = threadIdx.x;

    const float* Wbase;
    int kofs;
    if (kb < 4) { Wbase = Wx_l; kofs = kb * 256; }
    else        { Wbase = Wh_l; kofs = (kb - 4) * 256; }

    // stage W: 32 rows x 256 fp32 = 2048 float4, convert -> bf16 LDS
    #pragma unroll 4
    for (int ch = tid; ch < 2048; ch += 128) {
        int row = ch >> 6;            // 64 float4 per row
        int pos = ch & 63;
        float4 v = *(const float4*)(Wbase + (size_t)(n0 + row) * 1024 + kofs + pos * 4);
        __bf16* d = &Wl[row][pos * 4];
        d[0] = (__bf16)v.x; d[1] = (__bf16)v.y;
        d[2] = (__bf16)v.z; d[3] = (__bf16)v.w;
    }
    // stage X: 64 rows x 256 bf16 = 2048 16B chunks of 8 bf16
    const int xko = kb * 256;
    #pragma unroll 4
    for (int ch = tid; ch < 2048; ch += 128) {
        int row = ch >> 5;            // 32 chunks per row
        int pos = ch & 31;
        uint4 v = *(const uint4*)(xh + (size_t)row * 2048 + xko + pos * 8);
        *(uint4*)&Xl[row][pos * 8] = v;
    }
    __syncthreads();

    const int wave = tid >> 6;
    const int lane = tid & 63;
    const int c16 = lane & 15;
    const int kq = (lane >> 4) * 8;
    const int col = wave * 16 + c16;  // local col 0..31

    floatx4 acc[4] = {{0.f,0.f,0.f,0.f},{0.f,0.f,0.f,0.f},
                      {0.f,0.f,0.f,0.f},{0.f,0.f,0.f,0.f}};
    #pragma unroll
    for (int ks = 0; ks < 8; ++ks) {
        bf16x8 bfrag = *(const bf16x8*)&Wl[col][ks * 32 + kq];
        #pragma unroll
        for (int sub = 0; sub < 4; ++sub) {
            bf16x8 afrag = *(const bf16x8*)&Xl[sub * 16 + c16][ks * 32 + kq];
            acc[sub] = __builtin_amdgcn_mfma_f32_16x16x32_bf16(afrag, bfrag, acc[sub], 0, 0, 0);
        }
    }

    float* pdst = part + (size_t)kb * 64 * 4096;
    const int ncol = n0 + col;
    #pragma unroll
    for (int sub = 0; sub < 4; ++sub) {
        #pragma unroll
        for (int r = 0; r < 4; ++r) {
            int m = sub * 16 + (lane >> 4) * 4 + r;  // batch index
            pdst[(size_t)m * 4096 + ncol] = acc[sub][r];
        }
    }
}

// ---------------------------------------------------------------------------
// Kernel 3 (per layer): reduce partials + bias + LoRA + activations
//   one thread per (b,h); writes h_new/c_new into d_out slots
// ---------------------------------------------------------------------------
__global__ __launch_bounds__(256) void cell_kernel(
    const float* __restrict__ part,   // [8][64][4096]
    const float* __restrict__ bx_l,   // [G,H]
    const float* __restrict__ bh_l,   // [G,H]
    const float* __restrict__ Bx_l,   // [G,H,R]
    const float* __restrict__ Bh_l,   // [G,H,R]
    const float* __restrict__ t_x,    // [G,B,R]
    const float* __restrict__ t_h,    // [G,B,R]
    const float* __restrict__ c0_l,   // [B,H]
    float* __restrict__ h_out,        // [B,H]
    float* __restrict__ c_out,        // [B,H]
    float* __restrict__ out_final)    // [B,H] or nullptr
{
    int idx = blockIdx.x * 256 + threadIdx.x;   // 0..65535
    int b = idx >> 10;
    int h = idx & 1023;

    float pre[4];
    #pragma unroll
    for (int g = 0; g < 4; ++g) {
        int n = g * 1024 + h;
        float s = bx_l[n] + bh_l[n];
        #pragma unroll
        for (int kk = 0; kk < 8; ++kk)
            s += part[(size_t)kk * 262144 + (size_t)b * 4096 + n];
        // LoRA: sum_r B[g,h,r] * t[g,b,r]
        const float4* Bx4 = (const float4*)(Bx_l + (size_t)n * 16);
        const float4* Bh4 = (const float4*)(Bh_l + (size_t)n * 16);
        const float4* tx4 = (const float4*)(t_x + (size_t)(g * 64 + b) * 16);
        const float4* th4 = (const float4*)(t_h + (size_t)(g * 64 + b) * 16);
        #pragma unroll
        for (int q = 0; q < 4; ++q) {
            float4 bx = Bx4[q], tx = tx4[q];
            s += bx.x * tx.x + bx.y * tx.y + bx.z * tx.z + bx.w * tx.w;
            float4 bh = Bh4[q], th = th4[q];
            s += bh.x * th.x + bh.y * th.y + bh.z * th.z + bh.w * th.w;
        }
        pre[g] = s;
    }

    float it = 1.f / (1.f + __expf(-pre[0]));
    float ft = 1.f / (1.f + __expf(-pre[1]));
    float gt = tanhf(pre[2]);
    float ot = 1.f / (1.f + __expf(-pre[3]));
    float c = ft * c0_l[idx] + it * gt;
    float hn = ot * tanhf(c);

    h_out[idx] = hn;
    c_out[idx] = c;
    if (out_final) out_final[idx] = hn;
}

// ---------------------------------------------------------------------------
extern "C" void kernel_launch(void* const* d_in, const int* in_sizes, int n_in,
                              void* d_out, int out_size, void* d_ws, size_t ws_size,
                              hipStream_t stream) {
    const float* input_seq = (const float*)d_in[0];
    const float* h0  = (const float*)d_in[1];
    const float* c0  = (const float*)d_in[2];
    const float* W_x = (const float*)d_in[3];
    const float* W_h = (const float*)d_in[4];
    const float* b_x = (const float*)d_in[5];
    const float* b_h = (const float*)d_in[6];
    const float* A_x = (const float*)d_in[7];
    const float* B_x = (const float*)d_in[8];
    const float* A_h = (const float*)d_in[9];
    const float* B_h = (const float*)d_in[10];

    float* out = (float*)d_out;                 // [B,H]
    float* h_t = out + B_ * H_;                 // [L,B,H]
    float* c_t = h_t + L_ * B_ * H_;            // [L,B,H]

    // ws layout: xh bf16 (256KB) | t_x (16KB) | t_h (16KB) | pad | part (8MB)
    char* ws = (char*)d_ws;
    __bf16* xh = (__bf16*)ws;
    float* t_x = (float*)(ws + 256 * 1024);
    float* t_h = t_x + G_ * B_ * R_;
    float* part = (float*)(ws + 512 * 1024);    // [8][64][4096] fp32 = 8 MB

    const float* x_last = input_seq + (size_t)(T_ - 1) * B_ * I_;

    for (int l = 0; l < L_; ++l) {
        const float* x_src = (l == 0) ? x_last : (h_t + (size_t)(l - 1) * B_ * H_);
        const float* h_src = h0 + (size_t)l * B_ * H_;

        prep_kernel<<<8704, 64, 0, stream>>>(
            x_src, h_src,
            A_x + (size_t)l * G_ * R_ * I_,
            A_h + (size_t)l * G_ * R_ * H_,
            t_x, t_h, xh);

        gemm_kernel<<<dim3(128, 8), 128, 0, stream>>>(
            W_x + (size_t)l * G_ * H_ * I_,
            W_h + (size_t)l * G_ * H_ * H_,
            xh, part);

        cell_kernel<<<256, 256, 0, stream>>>(
            part,
            b_x + (size_t)l * G_ * H_, b_h + (size_t)l * G_ * H_,
            B_x + (size_t)l * G_ * H_ * R_, B_h + (size_t)l * G_ * H_ * R_,
            t_x, t_h,
            c0 + (size_t)l * B_ * H_,
            h_t + (size_t)l * B_ * H_, c_t + (size_t)l * B_ * H_,
            (l == L_ - 1) ? out : nullptr);
    }
}